// Round 4
// baseline (574.153 us; speedup 1.0000x reference)
//
#include <hip/hip_runtime.h>
#include <math.h>

#define T_TOK 4096
#define D_DIM 1024
#define E_EXP 8
#define F_DIM 4096
#define BM 128
#define BN 128
#define BK 32
#define LDK 40          // legacy fallback pad
#define MAX_TILES 40    // sum_e ceil(cnt_e/128) <= 4096/128 + 7 = 39
#define KSPLIT 4        // gemm2 split-K factor (occupancy fix)

typedef __attribute__((ext_vector_type(8))) short short8;
typedef __attribute__((ext_vector_type(4))) float float4v;

__device__ __forceinline__ short f2b(float f) {
    union { float f; unsigned u; } v; v.f = f;
    unsigned r = v.u + 0x7fffu + ((v.u >> 16) & 1u);   // RNE to bf16
    return (short)(r >> 16);
}

// async 16B global -> LDS (wave-uniform LDS base + lane*16, per-lane global src)
__device__ __forceinline__ void gll16(const short* g, short* l) {
    __builtin_amdgcn_global_load_lds((const __attribute__((address_space(1))) unsigned*)g,
                                     (__attribute__((address_space(3))) unsigned*)l, 16, 0, 0);
}

// ---------------- router: fp32 logits + argmax (exact routing) + x->bf16 fused ----------------
__global__ void router_kernel(const float* __restrict__ x, const float* __restrict__ gw,
                              short* __restrict__ xb,
                              int* __restrict__ eid, int* __restrict__ rnk,
                              int* __restrict__ counts) {
    int lane = threadIdx.x & 63;
    int wave = threadIdx.x >> 6;
    int t = blockIdx.x * 4 + wave;
    const float* xr = x + (size_t)t * D_DIM;
    float p[E_EXP];
#pragma unroll
    for (int e = 0; e < E_EXP; ++e) p[e] = 0.f;
#pragma unroll
    for (int i = 0; i < D_DIM / 64; ++i) {
        float v = xr[lane + 64 * i];
        if (xb) xb[(size_t)t * D_DIM + lane + 64 * i] = f2b(v);   // fused bf16 convert
#pragma unroll
        for (int e = 0; e < E_EXP; ++e)
            p[e] = fmaf(v, gw[e * D_DIM + lane + 64 * i], p[e]);
    }
#pragma unroll
    for (int off = 32; off > 0; off >>= 1) {
#pragma unroll
        for (int e = 0; e < E_EXP; ++e) p[e] += __shfl_down(p[e], off, 64);
    }
    if (lane == 0) {
        int best = 0; float bv = p[0];
#pragma unroll
        for (int e = 1; e < E_EXP; ++e) if (p[e] > bv) { bv = p[e]; best = e; }
        eid[t] = best;
        rnk[t] = atomicAdd(&counts[best], 1);
    }
}

// ---------------- prefix + tile map (one wave, lane-parallel tmap fill) ----------------
__global__ void prefix_kernel(const int* __restrict__ counts, int* __restrict__ offsets,
                              int* __restrict__ tmap) {
    __shared__ int cnt[E_EXP], off[E_EXP + 1], tp[E_EXP + 1];
    int lane = threadIdx.x;
    if (lane < E_EXP) cnt[lane] = counts[lane];
    __syncthreads();
    if (lane == 0) {
        int o = 0, tv = 0;
        off[0] = 0; tp[0] = 0;
        for (int e = 0; e < E_EXP; ++e) {
            o += cnt[e];
            tv += (cnt[e] + BM - 1) / BM;
            off[e + 1] = o; tp[e + 1] = tv;
        }
    }
    __syncthreads();
    if (lane < E_EXP + 1) offsets[lane] = off[lane];
    if (lane < MAX_TILES) {
        int e = 0;
        while (e < E_EXP && tp[e + 1] <= lane) ++e;
        if (e < E_EXP) {
            int m0 = (lane - tp[e]) * BM;
            int c = cnt[e];
            tmap[lane * 3 + 0] = e;
            tmap[lane * 3 + 1] = off[e] + m0;
            tmap[lane * 3 + 2] = (c - m0 < BM) ? (c - m0) : BM;
        } else {
            tmap[lane * 3 + 2] = 0;
        }
    }
}

__global__ void scatter_kernel(const int* __restrict__ eid, const int* __restrict__ rnk,
                               const int* __restrict__ offsets, int* __restrict__ sorted) {
    int t = blockIdx.x * 256 + threadIdx.x;
    sorted[offsets[eid[t]] + rnk[t]] = t;
}

// ---------------- weights: fp32 [R][C] -> bf16 [C][R] (per expert slab) ----------------
__global__ __launch_bounds__(256) void tconv_kernel(const float* __restrict__ in,
                                                    short* __restrict__ outp, int R, int C) {
    __shared__ short t[64][72];
    size_t slab = (size_t)R * C;
    const float* ip = in + (size_t)blockIdx.z * slab + (size_t)(blockIdx.y * 64) * C + blockIdx.x * 64;
    short* op = outp + (size_t)blockIdx.z * slab + (size_t)(blockIdx.x * 64) * R + blockIdx.y * 64;
    int tid = threadIdx.x;
    int r = tid >> 2, c4 = (tid & 3) * 16;
    const float* p = ip + (size_t)r * C + c4;
    float4v f0 = *(const float4v*)(p);
    float4v f1 = *(const float4v*)(p + 4);
    float4v f2 = *(const float4v*)(p + 8);
    float4v f3 = *(const float4v*)(p + 12);
#pragma unroll
    for (int j = 0; j < 4; ++j) {
        t[c4 + j][r]      = f2b(f0[j]);
        t[c4 + 4 + j][r]  = f2b(f1[j]);
        t[c4 + 8 + j][r]  = f2b(f2[j]);
        t[c4 + 12 + j][r] = f2b(f3[j]);
    }
    __syncthreads();
    short* q = op + (size_t)r * R + c4;
    *(short8*)q       = *(const short8*)&t[r][c4];
    *(short8*)(q + 8) = *(const short8*)&t[r][c4 + 8];
}

// ============ grouped GEMM1: 2-phase dbuf global_load_lds pipeline + XCD chunking ============
// w1b layout: [e][n=f][k=d]. LDS [row][BK=32], 16B chunk c stored at c ^ ((row>>1)&3).
__global__ __launch_bounds__(256) void gemm1_bf16(const short* __restrict__ xb,
                                                  const short* __restrict__ w1b,
                                                  const int* __restrict__ sorted,
                                                  const int* __restrict__ tmap,
                                                  short* __restrict__ hbuf) {
    __shared__ short As[2][BM * BK];
    __shared__ short Bs[2][BN * BK];
    __shared__ int srow[BM];
    // XCD-chunked bijective swizzle: nwg = 32*40 = 1280 = 8 * 160
    int flat = blockIdx.y * 32 + blockIdx.x;
    int swz = (flat & 7) * 160 + (flat >> 3);
    int bx = swz & 31;
    int mt = swz >> 5;
    int m_count = tmap[mt * 3 + 2];
    if (m_count == 0) return;
    int e = tmap[mt * 3 + 0];
    int row0 = tmap[mt * 3 + 1];
    int n0 = bx * BN;
    int tid = threadIdx.x;
    if (tid < BM) srow[tid] = sorted[row0 + (tid < m_count ? tid : m_count - 1)];
    __syncthreads();

    int lane = tid & 63, wave = tid >> 6;
    int wm = (wave & 1) * 64, wn = (wave >> 1) * 64;
    float4v acc[4][4];
#pragma unroll
    for (int i = 0; i < 4; ++i)
#pragma unroll
        for (int j = 0; j < 4; ++j) acc[i][j] = (float4v)(0.f);

    int r0 = wave * 16 + (lane >> 2);
    int r1 = r0 + 64;
    int p0 = ((lane & 3) ^ ((r0 >> 1) & 3)) * 8;
    int p1 = ((lane & 3) ^ ((r1 >> 1) & 3)) * 8;
    const short* ag0 = xb + (size_t)srow[r0] * D_DIM + p0;
    const short* ag1 = xb + (size_t)srow[r1] * D_DIM + p1;
    const short* wb = w1b + (size_t)e * D_DIM * F_DIM;
    const short* bg0 = wb + (size_t)(n0 + r0) * D_DIM + p0;
    const short* bg1 = wb + (size_t)(n0 + r1) * D_DIM + p1;
    int lofs = wave * 512;

    int rfa = lane & 15;
    int clog = lane >> 4;
    int aoff[4], boff[4];
#pragma unroll
    for (int i = 0; i < 4; ++i) {
        int rowa = wm + i * 16 + rfa;
        aoff[i] = rowa * BK + ((clog ^ ((rowa >> 1) & 3)) * 8);
        int rowb = wn + i * 16 + rfa;
        boff[i] = rowb * BK + ((clog ^ ((rowb >> 1) & 3)) * 8);
    }

    // prologue: stage tile 0 into buf 0
    gll16(ag0, &As[0][lofs]);
    gll16(ag1, &As[0][lofs + 2048]);
    gll16(bg0, &Bs[0][lofs]);
    gll16(bg1, &Bs[0][lofs + 2048]);
    __syncthreads();

    const int NT = D_DIM / BK;
    int cur = 0;
    for (int t = 0; t < NT; ++t) {
        if (t + 1 < NT) {                       // issue next-tile loads EARLY (2-phase)
            int kn = (t + 1) * BK;
            gll16(ag0 + kn, &As[cur ^ 1][lofs]);
            gll16(ag1 + kn, &As[cur ^ 1][lofs + 2048]);
            gll16(bg0 + kn, &Bs[cur ^ 1][lofs]);
            gll16(bg1 + kn, &Bs[cur ^ 1][lofs + 2048]);
        }
        short8 af[4], bfr[4];
#pragma unroll
        for (int i = 0; i < 4; ++i) af[i] = *(const short8*)(&As[cur][aoff[i]]);
#pragma unroll
        for (int j = 0; j < 4; ++j) bfr[j] = *(const short8*)(&Bs[cur][boff[j]]);
#pragma unroll
        for (int i = 0; i < 4; ++i)
#pragma unroll
            for (int j = 0; j < 4; ++j)
                acc[i][j] = __builtin_amdgcn_mfma_f32_16x16x32_bf16(af[i], bfr[j], acc[i][j], 0, 0, 0);
        __syncthreads();                        // one barrier/iter: drains stage + protects LDS
        cur ^= 1;
    }
    int rbase = (lane >> 4) * 4;
    int cbase = lane & 15;
#pragma unroll
    for (int i = 0; i < 4; ++i) {
#pragma unroll
        for (int r = 0; r < 4; ++r) {
            int row = wm + i * 16 + rbase + r;
            if (row < m_count) {
                short* hp = hbuf + (size_t)(row0 + row) * F_DIM + n0 + wn + cbase;
#pragma unroll
                for (int j = 0; j < 4; ++j) {
                    float s = acc[i][j][r];
                    float g = 0.5f * s * (1.f + erff(s * 0.70710678118f));
                    hp[j * 16] = f2b(g);
                }
            }
        }
    }
}

// ============ grouped GEMM2: 2-phase dbuf + split-K atomics + XCD chunking ============
// w2b layout: [e][n=d][k=f].
__global__ __launch_bounds__(256) void gemm2_bf16(const short* __restrict__ hbuf,
                                                  const short* __restrict__ w2b,
                                                  const int* __restrict__ sorted,
                                                  const int* __restrict__ tmap,
                                                  float* __restrict__ out) {
    __shared__ short As[2][BM * BK];
    __shared__ short Bs[2][BN * BK];
    __shared__ int srow[BM];
    // XCD-chunked bijective swizzle: nwg = 8*40*4 = 1280 = 8 * 160
    int flat = (blockIdx.z * 40 + blockIdx.y) * 8 + blockIdx.x;
    int swz = (flat & 7) * 160 + (flat >> 3);
    int bx = swz & 7;
    int rest = swz >> 3;          // 0..159
    int mt = rest % 40;
    int kz = rest / 40;
    int m_count = tmap[mt * 3 + 2];
    if (m_count == 0) return;
    int e = tmap[mt * 3 + 0];
    int row0 = tmap[mt * 3 + 1];
    int n0 = bx * BN;
    int ks0 = kz * (F_DIM / KSPLIT);
    int tid = threadIdx.x;
    if (tid < BM) srow[tid] = sorted[row0 + (tid < m_count ? tid : m_count - 1)];
    __syncthreads();

    int lane = tid & 63, wave = tid >> 6;
    int wm = (wave & 1) * 64, wn = (wave >> 1) * 64;
    float4v acc[4][4];
#pragma unroll
    for (int i = 0; i < 4; ++i)
#pragma unroll
        for (int j = 0; j < 4; ++j) acc[i][j] = (float4v)(0.f);

    int r0 = wave * 16 + (lane >> 2);
    int r1 = r0 + 64;
    int p0 = ((lane & 3) ^ ((r0 >> 1) & 3)) * 8;
    int p1 = ((lane & 3) ^ ((r1 >> 1) & 3)) * 8;
    int cr0 = r0 < m_count ? r0 : m_count - 1;
    int cr1 = r1 < m_count ? r1 : m_count - 1;
    const short* ag0 = hbuf + (size_t)(row0 + cr0) * F_DIM + ks0 + p0;
    const short* ag1 = hbuf + (size_t)(row0 + cr1) * F_DIM + ks0 + p1;
    const short* wb = w2b + (size_t)e * F_DIM * D_DIM;
    const short* bg0 = wb + (size_t)(n0 + r0) * F_DIM + ks0 + p0;
    const short* bg1 = wb + (size_t)(n0 + r1) * F_DIM + ks0 + p1;
    int lofs = wave * 512;

    int rfa = lane & 15;
    int clog = lane >> 4;
    int aoff[4], boff[4];
#pragma unroll
    for (int i = 0; i < 4; ++i) {
        int rowa = wm + i * 16 + rfa;
        aoff[i] = rowa * BK + ((clog ^ ((rowa >> 1) & 3)) * 8);
        int rowb = wn + i * 16 + rfa;
        boff[i] = rowb * BK + ((clog ^ ((rowb >> 1) & 3)) * 8);
    }

    gll16(ag0, &As[0][lofs]);
    gll16(ag1, &As[0][lofs + 2048]);
    gll16(bg0, &Bs[0][lofs]);
    gll16(bg1, &Bs[0][lofs + 2048]);
    __syncthreads();

    const int NT = (F_DIM / KSPLIT) / BK;
    int cur = 0;
    for (int t = 0; t < NT; ++t) {
        if (t + 1 < NT) {
            int kn = (t + 1) * BK;
            gll16(ag0 + kn, &As[cur ^ 1][lofs]);
            gll16(ag1 + kn, &As[cur ^ 1][lofs + 2048]);
            gll16(bg0 + kn, &Bs[cur ^ 1][lofs]);
            gll16(bg1 + kn, &Bs[cur ^ 1][lofs + 2048]);
        }
        short8 af[4], bfr[4];
#pragma unroll
        for (int i = 0; i < 4; ++i) af[i] = *(const short8*)(&As[cur][aoff[i]]);
#pragma unroll
        for (int j = 0; j < 4; ++j) bfr[j] = *(const short8*)(&Bs[cur][boff[j]]);
#pragma unroll
        for (int i = 0; i < 4; ++i)
#pragma unroll
            for (int j = 0; j < 4; ++j)
                acc[i][j] = __builtin_amdgcn_mfma_f32_16x16x32_bf16(af[i], bfr[j], acc[i][j], 0, 0, 0);
        __syncthreads();
        cur ^= 1;
    }
    int rbase = (lane >> 4) * 4;
    int cbase = lane & 15;
#pragma unroll
    for (int i = 0; i < 4; ++i) {
#pragma unroll
        for (int r = 0; r < 4; ++r) {
            int row = wm + i * 16 + rbase + r;
            if (row < m_count) {
                float* op = out + (size_t)srow[row] * D_DIM + n0 + wn + cbase;
#pragma unroll
                for (int j = 0; j < 4; ++j) atomicAdd(op + j * 16, acc[i][j][r]);
            }
        }
    }
}

// ================= legacy fp32-weight path (fallback if workspace too small) =================
__global__ __launch_bounds__(256) void gemm1_kernel(const float* __restrict__ x,
                                                    const float* __restrict__ w1,
                                                    const int* __restrict__ sorted,
                                                    const int* __restrict__ tmap,
                                                    short* __restrict__ hbuf) {
    __shared__ short As[BM * LDK];
    __shared__ short Bs[BN * LDK];
    __shared__ int srow[BM];
    int mt = blockIdx.y;
    int m_count = tmap[mt * 3 + 2];
    if (m_count == 0) return;
    int e = tmap[mt * 3 + 0];
    int row0 = tmap[mt * 3 + 1];
    int n0 = blockIdx.x * BN;
    int tid = threadIdx.x;
    if (tid < BM) srow[tid] = sorted[row0 + (tid < m_count ? tid : m_count - 1)];
    __syncthreads();

    int lane = tid & 63, wave = tid >> 6;
    int wm = (wave & 1) * 64, wn = (wave >> 1) * 64;
    float4v acc[4][4];
#pragma unroll
    for (int i = 0; i < 4; ++i)
#pragma unroll
        for (int j = 0; j < 4; ++j) acc[i][j] = (float4v)(0.f);

    int ar = tid >> 1;
    int ac = (tid & 1) * 16;
    int bn = tid & 127;
    int bq = (tid >> 7) * 16;
    const float* abase = x + (size_t)srow[ar] * D_DIM + ac;
    const float* bbase = w1 + (size_t)e * D_DIM * F_DIM + (size_t)bq * F_DIM + (n0 + bn);

    for (int k0 = 0; k0 < D_DIM; k0 += BK) {
        {
            const float* ap = abase + k0;
            float4v f0 = *(const float4v*)(ap);
            float4v f1 = *(const float4v*)(ap + 4);
            float4v f2 = *(const float4v*)(ap + 8);
            float4v f3 = *(const float4v*)(ap + 12);
            short8 s0, s1;
#pragma unroll
            for (int c = 0; c < 4; ++c) {
                s0[c] = f2b(f0[c]); s0[4 + c] = f2b(f1[c]);
                s1[c] = f2b(f2[c]); s1[4 + c] = f2b(f3[c]);
            }
            *(short8*)(&As[ar * LDK + ac]) = s0;
            *(short8*)(&As[ar * LDK + ac + 8]) = s1;
        }
        {
            const float* bp = bbase + (size_t)k0 * F_DIM;
            float v[16];
#pragma unroll
            for (int j = 0; j < 16; ++j) v[j] = bp[(size_t)j * F_DIM];
            short8 s0, s1;
#pragma unroll
            for (int j = 0; j < 8; ++j) { s0[j] = f2b(v[j]); s1[j] = f2b(v[8 + j]); }
            *(short8*)(&Bs[bn * LDK + bq]) = s0;
            *(short8*)(&Bs[bn * LDK + bq + 8]) = s1;
        }
        __syncthreads();
        short8 af[4], bfr[4];
#pragma unroll
        for (int i = 0; i < 4; ++i)
            af[i] = *(const short8*)(&As[(wm + i * 16 + (lane & 15)) * LDK + (lane >> 4) * 8]);
#pragma unroll
        for (int j = 0; j < 4; ++j)
            bfr[j] = *(const short8*)(&Bs[(wn + j * 16 + (lane & 15)) * LDK + (lane >> 4) * 8]);
#pragma unroll
        for (int i = 0; i < 4; ++i)
#pragma unroll
            for (int j = 0; j < 4; ++j)
                acc[i][j] = __builtin_amdgcn_mfma_f32_16x16x32_bf16(af[i], bfr[j], acc[i][j], 0, 0, 0);
        __syncthreads();
    }
    int rbase = (lane >> 4) * 4;
    int cbase = lane & 15;
#pragma unroll
    for (int i = 0; i < 4; ++i) {
#pragma unroll
        for (int r = 0; r < 4; ++r) {
            int row = wm + i * 16 + rbase + r;
            if (row < m_count) {
                short* hp = hbuf + (size_t)(row0 + row) * F_DIM + n0 + wn + cbase;
#pragma unroll
                for (int j = 0; j < 4; ++j) {
                    float s = acc[i][j][r];
                    float g = 0.5f * s * (1.f + erff(s * 0.70710678118f));
                    hp[j * 16] = f2b(g);
                }
            }
        }
    }
}

__global__ __launch_bounds__(256) void gemm2_kernel(const short* __restrict__ hbuf,
                                                    const float* __restrict__ w2,
                                                    const int* __restrict__ sorted,
                                                    const int* __restrict__ tmap,
                                                    float* __restrict__ out) {
    __shared__ short As[BM * LDK];
    __shared__ short Bs[BN * LDK];
    __shared__ int srow[BM];
    int mt = blockIdx.y;
    int m_count = tmap[mt * 3 + 2];
    if (m_count == 0) return;
    int e = tmap[mt * 3 + 0];
    int row0 = tmap[mt * 3 + 1];
    int n0 = blockIdx.x * BN;
    int tid = threadIdx.x;
    if (tid < BM) srow[tid] = sorted[row0 + (tid < m_count ? tid : m_count - 1)];
    __syncthreads();

    int lane = tid & 63, wave = tid >> 6;
    int wm = (wave & 1) * 64, wn = (wave >> 1) * 64;
    float4v acc[4][4];
#pragma unroll
    for (int i = 0; i < 4; ++i)
#pragma unroll
        for (int j = 0; j < 4; ++j) acc[i][j] = (float4v)(0.f);

    int ar = tid >> 1;
    int ac = (tid & 1) * 16;
    int bn = tid & 127;
    int bq = (tid >> 7) * 16;
    int arc = ar < m_count ? ar : m_count - 1;
    const short* abase = hbuf + (size_t)(row0 + arc) * F_DIM + ac;
    const float* bbase = w2 + (size_t)e * F_DIM * D_DIM + (size_t)bq * D_DIM + (n0 + bn);

    for (int k0 = 0; k0 < F_DIM; k0 += BK) {
        {
            const short* ap = abase + k0;
            *(short8*)(&As[ar * LDK + ac]) = *(const short8*)(ap);
            *(short8*)(&As[ar * LDK + ac + 8]) = *(const short8*)(ap + 8);
        }
        {
            const float* bp = bbase + (size_t)k0 * D_DIM;
            float v[16];
#pragma unroll
            for (int j = 0; j < 16; ++j) v[j] = bp[(size_t)j * D_DIM];
            short8 s0, s1;
#pragma unroll
            for (int j = 0; j < 8; ++j) { s0[j] = f2b(v[j]); s1[j] = f2b(v[8 + j]); }
            *(short8*)(&Bs[bn * LDK + bq]) = s0;
            *(short8*)(&Bs[bn * LDK + bq + 8]) = s1;
        }
        __syncthreads();
        short8 af[4], bfr[4];
#pragma unroll
        for (int i = 0; i < 4; ++i)
            af[i] = *(const short8*)(&As[(wm + i * 16 + (lane & 15)) * LDK + (lane >> 4) * 8]);
#pragma unroll
        for (int j = 0; j < 4; ++j)
            bfr[j] = *(const short8*)(&Bs[(wn + j * 16 + (lane & 15)) * LDK + (lane >> 4) * 8]);
#pragma unroll
        for (int i = 0; i < 4; ++i)
#pragma unroll
            for (int j = 0; j < 4; ++j)
                acc[i][j] = __builtin_amdgcn_mfma_f32_16x16x32_bf16(af[i], bfr[j], acc[i][j], 0, 0, 0);
        __syncthreads();
    }
    int rbase = (lane >> 4) * 4;
    int cbase = lane & 15;
#pragma unroll
    for (int i = 0; i < 4; ++i) {
#pragma unroll
        for (int r = 0; r < 4; ++r) {
            int row = wm + i * 16 + rbase + r;
            if (row < m_count) {
                float* op = out + (size_t)srow[row] * D_DIM + n0 + wn + cbase;
#pragma unroll
                for (int j = 0; j < 4; ++j) op[j * 16] = acc[i][j][r];
            }
        }
    }
}

extern "C" void kernel_launch(void* const* d_in, const int* in_sizes, int n_in,
                              void* d_out, int out_size, void* d_ws, size_t ws_size,
                              hipStream_t stream) {
    const float* x  = (const float*)d_in[0];
    const float* gw = (const float*)d_in[1];
    const float* w1 = (const float*)d_in[2];
    const float* w2 = (const float*)d_in[3];
    float* out = (float*)d_out;
    char* ws = (char*)d_ws;

    int* counts  = (int*)(ws);            // 8 ints
    int* offsets = (int*)(ws + 64);       // 9 ints
    int* tmap    = (int*)(ws + 128);      // 40*3 ints
    int* eid     = (int*)(ws + 1024);     // 4096 ints
    int* rnk     = (int*)(ws + 17408);    // 4096 ints
    int* sorted  = (int*)(ws + 33792);    // 4096 ints
    short* hbuf  = (short*)(ws + 51200);  // 4096*4096 bf16 = 33.55 MB

    const size_t HB  = 33554432ull;       // hbuf bytes
    const size_t XB  = 8388608ull;        // xb bytes  (4096*1024*2)
    const size_t WB  = 67108864ull;       // w1b/w2b bytes each (8*1024*4096*2)
    short* xb  = (short*)(ws + 51200 + HB);
    short* w1b = (short*)(ws + 51200 + HB + XB);
    short* w2b = (short*)(ws + 51200 + HB + XB + WB);
    const size_t need = 51200ull + HB + XB + 2ull * WB;   // ~176.2 MB
    bool fast = ws_size >= need;

    hipMemsetAsync(counts, 0, 32, stream);
    router_kernel<<<T_TOK / 4, 256, 0, stream>>>(x, gw, fast ? xb : (short*)0, eid, rnk, counts);

    if (fast) {
        hipMemsetAsync(out, 0, (size_t)T_TOK * D_DIM * 4, stream);
        // w1: [e][d=1024][f=4096] -> w1b [e][f][d]
        tconv_kernel<<<dim3(F_DIM / 64, D_DIM / 64, E_EXP), 256, 0, stream>>>(w1, w1b, D_DIM, F_DIM);
        // w2: [e][f=4096][d=1024] -> w2b [e][d][f]
        tconv_kernel<<<dim3(D_DIM / 64, F_DIM / 64, E_EXP), 256, 0, stream>>>(w2, w2b, F_DIM, D_DIM);
    }

    prefix_kernel<<<1, 64, 0, stream>>>(counts, offsets, tmap);
    scatter_kernel<<<T_TOK / 256, 256, 0, stream>>>(eid, rnk, offsets, sorted);

    if (fast) {
        gemm1_bf16<<<dim3(F_DIM / BN, MAX_TILES), 256, 0, stream>>>(xb, w1b, sorted, tmap, hbuf);
        gemm2_bf16<<<dim3(D_DIM / BN, MAX_TILES, KSPLIT), 256, 0, stream>>>(hbuf, w2b, sorted, tmap, out);
    } else {
        gemm1_kernel<<<dim3(F_DIM / BN, MAX_TILES), 256, 0, stream>>>(x, w1, sorted, tmap, hbuf);
        gemm2_kernel<<<dim3(D_DIM / BN, MAX_TILES), 256, 0, stream>>>(hbuf, w2, sorted, tmap, out);
    }
}

// Round 5
// 560.218 us; speedup vs baseline: 1.0249x; 1.0249x over previous
//
#include <hip/hip_runtime.h>
#include <math.h>

#define T_TOK 4096
#define D_DIM 1024
#define E_EXP 8
#define F_DIM 4096
#define BM 128
#define BN 128
#define BK 32
#define BUFE (BM * BK)  // 4096 bf16 elems = 8 KB per operand per pipeline stage
#define LDK 40          // legacy fallback pad
#define MAX_TILES 40    // sum_e ceil(cnt_e/128) <= 4096/128 + 7 = 39
#define KSPLIT 4        // gemm2 split-K factor (occupancy fix)

typedef __attribute__((ext_vector_type(8))) short short8;
typedef __attribute__((ext_vector_type(4))) float float4v;

__device__ __forceinline__ short f2b(float f) {
    union { float f; unsigned u; } v; v.f = f;
    unsigned r = v.u + 0x7fffu + ((v.u >> 16) & 1u);   // RNE to bf16
    return (short)(r >> 16);
}

// async 16B global -> LDS (wave-uniform LDS base + lane*16, per-lane global src)
__device__ __forceinline__ void gll16(const short* g, short* l) {
    __builtin_amdgcn_global_load_lds((const __attribute__((address_space(1))) unsigned*)g,
                                     (__attribute__((address_space(3))) unsigned*)l, 16, 0, 0);
}

// ---------------- router: fp32 logits + argmax (exact routing) + x->bf16 fused ----------------
__global__ void router_kernel(const float* __restrict__ x, const float* __restrict__ gw,
                              short* __restrict__ xb,
                              int* __restrict__ eid, int* __restrict__ rnk,
                              int* __restrict__ counts) {
    int lane = threadIdx.x & 63;
    int wave = threadIdx.x >> 6;
    int t = blockIdx.x * 4 + wave;
    const float* xr = x + (size_t)t * D_DIM;
    float p[E_EXP];
#pragma unroll
    for (int e = 0; e < E_EXP; ++e) p[e] = 0.f;
#pragma unroll
    for (int i = 0; i < D_DIM / 64; ++i) {
        float v = xr[lane + 64 * i];
        if (xb) xb[(size_t)t * D_DIM + lane + 64 * i] = f2b(v);   // fused bf16 convert
#pragma unroll
        for (int e = 0; e < E_EXP; ++e)
            p[e] = fmaf(v, gw[e * D_DIM + lane + 64 * i], p[e]);
    }
#pragma unroll
    for (int off = 32; off > 0; off >>= 1) {
#pragma unroll
        for (int e = 0; e < E_EXP; ++e) p[e] += __shfl_down(p[e], off, 64);
    }
    if (lane == 0) {
        int best = 0; float bv = p[0];
#pragma unroll
        for (int e = 1; e < E_EXP; ++e) if (p[e] > bv) { bv = p[e]; best = e; }
        eid[t] = best;
        rnk[t] = atomicAdd(&counts[best], 1);
    }
}

// ---------------- prefix + tile map (one wave, lane-parallel tmap fill) ----------------
__global__ void prefix_kernel(const int* __restrict__ counts, int* __restrict__ offsets,
                              int* __restrict__ tmap) {
    __shared__ int cnt[E_EXP], off[E_EXP + 1], tp[E_EXP + 1];
    int lane = threadIdx.x;
    if (lane < E_EXP) cnt[lane] = counts[lane];
    __syncthreads();
    if (lane == 0) {
        int o = 0, tv = 0;
        off[0] = 0; tp[0] = 0;
        for (int e = 0; e < E_EXP; ++e) {
            o += cnt[e];
            tv += (cnt[e] + BM - 1) / BM;
            off[e + 1] = o; tp[e + 1] = tv;
        }
    }
    __syncthreads();
    if (lane < E_EXP + 1) offsets[lane] = off[lane];
    if (lane < MAX_TILES) {
        int e = 0;
        while (e < E_EXP && tp[e + 1] <= lane) ++e;
        if (e < E_EXP) {
            int m0 = (lane - tp[e]) * BM;
            int c = cnt[e];
            tmap[lane * 3 + 0] = e;
            tmap[lane * 3 + 1] = off[e] + m0;
            tmap[lane * 3 + 2] = (c - m0 < BM) ? (c - m0) : BM;
        } else {
            tmap[lane * 3 + 2] = 0;
        }
    }
}

__global__ void scatter_kernel(const int* __restrict__ eid, const int* __restrict__ rnk,
                               const int* __restrict__ offsets, int* __restrict__ sorted) {
    int t = blockIdx.x * 256 + threadIdx.x;
    sorted[offsets[eid[t]] + rnk[t]] = t;
}

// ---------------- weights: fp32 [R][C] -> bf16 [C][R] (per expert slab) ----------------
__global__ __launch_bounds__(256) void tconv_kernel(const float* __restrict__ in,
                                                    short* __restrict__ outp, int R, int C) {
    __shared__ short t[64][72];
    size_t slab = (size_t)R * C;
    const float* ip = in + (size_t)blockIdx.z * slab + (size_t)(blockIdx.y * 64) * C + blockIdx.x * 64;
    short* op = outp + (size_t)blockIdx.z * slab + (size_t)(blockIdx.x * 64) * R + blockIdx.y * 64;
    int tid = threadIdx.x;
    int r = tid >> 2, c4 = (tid & 3) * 16;
    const float* p = ip + (size_t)r * C + c4;
    float4v f0 = *(const float4v*)(p);
    float4v f1 = *(const float4v*)(p + 4);
    float4v f2 = *(const float4v*)(p + 8);
    float4v f3 = *(const float4v*)(p + 12);
#pragma unroll
    for (int j = 0; j < 4; ++j) {
        t[c4 + j][r]      = f2b(f0[j]);
        t[c4 + 4 + j][r]  = f2b(f1[j]);
        t[c4 + 8 + j][r]  = f2b(f2[j]);
        t[c4 + 12 + j][r] = f2b(f3[j]);
    }
    __syncthreads();
    short* q = op + (size_t)r * R + c4;
    *(short8*)q       = *(const short8*)&t[r][c4];
    *(short8*)(q + 8) = *(const short8*)&t[r][c4 + 8];
}

// ====== grouped GEMM1: 3-deep pipeline (triple-buffer LDS, counted vmcnt) + XCD chunking ======
// w1b layout: [e][n=f][k=d]. LDS [row][BK=32], 16B chunk c stored at c ^ ((row>>1)&3).
__global__ __launch_bounds__(256) void gemm1_bf16(const short* __restrict__ xb,
                                                  const short* __restrict__ w1b,
                                                  const int* __restrict__ sorted,
                                                  const int* __restrict__ tmap,
                                                  short* __restrict__ hbuf) {
    __shared__ short As[3 * BUFE];
    __shared__ short Bs[3 * BUFE];
    __shared__ int srow[BM];
    // XCD-chunked bijective swizzle: nwg = 32*40 = 1280 = 8 * 160
    int flat = blockIdx.y * 32 + blockIdx.x;
    int swz = (flat & 7) * 160 + (flat >> 3);
    int bx = swz & 31;
    int mt = swz >> 5;
    int m_count = tmap[mt * 3 + 2];
    if (m_count == 0) return;
    int e = tmap[mt * 3 + 0];
    int row0 = tmap[mt * 3 + 1];
    int n0 = bx * BN;
    int tid = threadIdx.x;
    if (tid < BM) srow[tid] = sorted[row0 + (tid < m_count ? tid : m_count - 1)];
    __syncthreads();

    int lane = tid & 63, wave = tid >> 6;
    int wm = (wave & 1) * 64, wn = (wave >> 1) * 64;
    float4v acc[4][4];
#pragma unroll
    for (int i = 0; i < 4; ++i)
#pragma unroll
        for (int j = 0; j < 4; ++j) acc[i][j] = (float4v)(0.f);

    int r0 = wave * 16 + (lane >> 2);
    int r1 = r0 + 64;
    int p0 = ((lane & 3) ^ ((r0 >> 1) & 3)) * 8;
    int p1 = ((lane & 3) ^ ((r1 >> 1) & 3)) * 8;
    const short* ag0 = xb + (size_t)srow[r0] * D_DIM + p0;
    const short* ag1 = xb + (size_t)srow[r1] * D_DIM + p1;
    const short* wb = w1b + (size_t)e * D_DIM * F_DIM;
    const short* bg0 = wb + (size_t)(n0 + r0) * D_DIM + p0;
    const short* bg1 = wb + (size_t)(n0 + r1) * D_DIM + p1;
    int lofs = wave * 512;

    int rfa = lane & 15;
    int clog = lane >> 4;
    int aoff[4], boff[4];
#pragma unroll
    for (int i = 0; i < 4; ++i) {
        int rowa = wm + i * 16 + rfa;
        aoff[i] = rowa * BK + ((clog ^ ((rowa >> 1) & 3)) * 8);
        int rowb = wn + i * 16 + rfa;
        boff[i] = rowb * BK + ((clog ^ ((rowb >> 1) & 3)) * 8);
    }

    // prologue: tile0 -> buf0, tile1 -> buf1 (8 loads in flight)
    gll16(ag0,      As + lofs);
    gll16(ag1,      As + lofs + 2048);
    gll16(bg0,      Bs + lofs);
    gll16(bg1,      Bs + lofs + 2048);
    gll16(ag0 + BK, As + BUFE + lofs);
    gll16(ag1 + BK, As + BUFE + lofs + 2048);
    gll16(bg0 + BK, Bs + BUFE + lofs);
    gll16(bg1 + BK, Bs + BUFE + lofs + 2048);

    const int NT = D_DIM / BK;   // 32
    int cur = 0, nxt = 2;
    for (int t = 0; t < NT; ++t) {
        if (t + 2 < NT) {                           // issue tile t+2 (2 tiles ahead)
            int kn = (t + 2) * BK;
            int no = nxt * BUFE + lofs;
            gll16(ag0 + kn, As + no);
            gll16(ag1 + kn, As + no + 2048);
            gll16(bg0 + kn, Bs + no);
            gll16(bg1 + kn, Bs + no + 2048);
        }
        __builtin_amdgcn_sched_barrier(0);
        // counted wait: only tile t must have landed; newer tiles stay in flight
        if (t + 2 < NT)      asm volatile("s_waitcnt vmcnt(8)" ::: "memory");
        else if (t + 1 < NT) asm volatile("s_waitcnt vmcnt(4)" ::: "memory");
        else                 asm volatile("s_waitcnt vmcnt(0)" ::: "memory");
        __builtin_amdgcn_sched_barrier(0);
        __builtin_amdgcn_s_barrier();               // all waves' tile-t loads landed
        __builtin_amdgcn_sched_barrier(0);
        int co = cur * BUFE;
        short8 af[4], bfr[4];
#pragma unroll
        for (int i = 0; i < 4; ++i) af[i] = *(const short8*)(&As[co + aoff[i]]);
#pragma unroll
        for (int j = 0; j < 4; ++j) bfr[j] = *(const short8*)(&Bs[co + boff[j]]);
#pragma unroll
        for (int i = 0; i < 4; ++i)
#pragma unroll
            for (int j = 0; j < 4; ++j)
                acc[i][j] = __builtin_amdgcn_mfma_f32_16x16x32_bf16(af[i], bfr[j], acc[i][j], 0, 0, 0);
        __builtin_amdgcn_s_barrier();               // WAR guard before buf[cur] is restaged
        __builtin_amdgcn_sched_barrier(0);
        cur = (cur == 2) ? 0 : cur + 1;
        nxt = (nxt == 2) ? 0 : nxt + 1;
    }
    int rbase = (lane >> 4) * 4;
    int cbase = lane & 15;
#pragma unroll
    for (int i = 0; i < 4; ++i) {
#pragma unroll
        for (int r = 0; r < 4; ++r) {
            int row = wm + i * 16 + rbase + r;
            if (row < m_count) {
                short* hp = hbuf + (size_t)(row0 + row) * F_DIM + n0 + wn + cbase;
#pragma unroll
                for (int j = 0; j < 4; ++j) {
                    float s = acc[i][j][r];
                    float g = 0.5f * s * (1.f + erff(s * 0.70710678118f));
                    hp[j * 16] = f2b(g);
                }
            }
        }
    }
}

// ====== grouped GEMM2: 3-deep pipeline + split-K atomics + XCD chunking ======
// w2b layout: [e][n=d][k=f].
__global__ __launch_bounds__(256) void gemm2_bf16(const short* __restrict__ hbuf,
                                                  const short* __restrict__ w2b,
                                                  const int* __restrict__ sorted,
                                                  const int* __restrict__ tmap,
                                                  float* __restrict__ out) {
    __shared__ short As[3 * BUFE];
    __shared__ short Bs[3 * BUFE];
    __shared__ int srow[BM];
    // XCD-chunked bijective swizzle: nwg = 8*40*4 = 1280 = 8 * 160
    int flat = (blockIdx.z * 40 + blockIdx.y) * 8 + blockIdx.x;
    int swz = (flat & 7) * 160 + (flat >> 3);
    int bx = swz & 7;
    int rest = swz >> 3;          // 0..159
    int mt = rest % 40;
    int kz = rest / 40;
    int m_count = tmap[mt * 3 + 2];
    if (m_count == 0) return;
    int e = tmap[mt * 3 + 0];
    int row0 = tmap[mt * 3 + 1];
    int n0 = bx * BN;
    int ks0 = kz * (F_DIM / KSPLIT);
    int tid = threadIdx.x;
    if (tid < BM) srow[tid] = sorted[row0 + (tid < m_count ? tid : m_count - 1)];
    __syncthreads();

    int lane = tid & 63, wave = tid >> 6;
    int wm = (wave & 1) * 64, wn = (wave >> 1) * 64;
    float4v acc[4][4];
#pragma unroll
    for (int i = 0; i < 4; ++i)
#pragma unroll
        for (int j = 0; j < 4; ++j) acc[i][j] = (float4v)(0.f);

    int r0 = wave * 16 + (lane >> 2);
    int r1 = r0 + 64;
    int p0 = ((lane & 3) ^ ((r0 >> 1) & 3)) * 8;
    int p1 = ((lane & 3) ^ ((r1 >> 1) & 3)) * 8;
    int cr0 = r0 < m_count ? r0 : m_count - 1;
    int cr1 = r1 < m_count ? r1 : m_count - 1;
    const short* ag0 = hbuf + (size_t)(row0 + cr0) * F_DIM + ks0 + p0;
    const short* ag1 = hbuf + (size_t)(row0 + cr1) * F_DIM + ks0 + p1;
    const short* wb = w2b + (size_t)e * F_DIM * D_DIM;
    const short* bg0 = wb + (size_t)(n0 + r0) * F_DIM + ks0 + p0;
    const short* bg1 = wb + (size_t)(n0 + r1) * F_DIM + ks0 + p1;
    int lofs = wave * 512;

    int rfa = lane & 15;
    int clog = lane >> 4;
    int aoff[4], boff[4];
#pragma unroll
    for (int i = 0; i < 4; ++i) {
        int rowa = wm + i * 16 + rfa;
        aoff[i] = rowa * BK + ((clog ^ ((rowa >> 1) & 3)) * 8);
        int rowb = wn + i * 16 + rfa;
        boff[i] = rowb * BK + ((clog ^ ((rowb >> 1) & 3)) * 8);
    }

    gll16(ag0,      As + lofs);
    gll16(ag1,      As + lofs + 2048);
    gll16(bg0,      Bs + lofs);
    gll16(bg1,      Bs + lofs + 2048);
    gll16(ag0 + BK, As + BUFE + lofs);
    gll16(ag1 + BK, As + BUFE + lofs + 2048);
    gll16(bg0 + BK, Bs + BUFE + lofs);
    gll16(bg1 + BK, Bs + BUFE + lofs + 2048);

    const int NT = (F_DIM / KSPLIT) / BK;   // 32
    int cur = 0, nxt = 2;
    for (int t = 0; t < NT; ++t) {
        if (t + 2 < NT) {
            int kn = (t + 2) * BK;
            int no = nxt * BUFE + lofs;
            gll16(ag0 + kn, As + no);
            gll16(ag1 + kn, As + no + 2048);
            gll16(bg0 + kn, Bs + no);
            gll16(bg1 + kn, Bs + no + 2048);
        }
        __builtin_amdgcn_sched_barrier(0);
        if (t + 2 < NT)      asm volatile("s_waitcnt vmcnt(8)" ::: "memory");
        else if (t + 1 < NT) asm volatile("s_waitcnt vmcnt(4)" ::: "memory");
        else                 asm volatile("s_waitcnt vmcnt(0)" ::: "memory");
        __builtin_amdgcn_sched_barrier(0);
        __builtin_amdgcn_s_barrier();
        __builtin_amdgcn_sched_barrier(0);
        int co = cur * BUFE;
        short8 af[4], bfr[4];
#pragma unroll
        for (int i = 0; i < 4; ++i) af[i] = *(const short8*)(&As[co + aoff[i]]);
#pragma unroll
        for (int j = 0; j < 4; ++j) bfr[j] = *(const short8*)(&Bs[co + boff[j]]);
#pragma unroll
        for (int i = 0; i < 4; ++i)
#pragma unroll
            for (int j = 0; j < 4; ++j)
                acc[i][j] = __builtin_amdgcn_mfma_f32_16x16x32_bf16(af[i], bfr[j], acc[i][j], 0, 0, 0);
        __builtin_amdgcn_s_barrier();
        __builtin_amdgcn_sched_barrier(0);
        cur = (cur == 2) ? 0 : cur + 1;
        nxt = (nxt == 2) ? 0 : nxt + 1;
    }
    int rbase = (lane >> 4) * 4;
    int cbase = lane & 15;
#pragma unroll
    for (int i = 0; i < 4; ++i) {
#pragma unroll
        for (int r = 0; r < 4; ++r) {
            int row = wm + i * 16 + rbase + r;
            if (row < m_count) {
                float* op = out + (size_t)srow[row] * D_DIM + n0 + wn + cbase;
#pragma unroll
                for (int j = 0; j < 4; ++j) atomicAdd(op + j * 16, acc[i][j][r]);
            }
        }
    }
}

// ================= legacy fp32-weight path (fallback if workspace too small) =================
__global__ __launch_bounds__(256) void gemm1_kernel(const float* __restrict__ x,
                                                    const float* __restrict__ w1,
                                                    const int* __restrict__ sorted,
                                                    const int* __restrict__ tmap,
                                                    short* __restrict__ hbuf) {
    __shared__ short As[BM * LDK];
    __shared__ short Bs[BN * LDK];
    __shared__ int srow[BM];
    int mt = blockIdx.y;
    int m_count = tmap[mt * 3 + 2];
    if (m_count == 0) return;
    int e = tmap[mt * 3 + 0];
    int row0 = tmap[mt * 3 + 1];
    int n0 = blockIdx.x * BN;
    int tid = threadIdx.x;
    if (tid < BM) srow[tid] = sorted[row0 + (tid < m_count ? tid : m_count - 1)];
    __syncthreads();

    int lane = tid & 63, wave = tid >> 6;
    int wm = (wave & 1) * 64, wn = (wave >> 1) * 64;
    float4v acc[4][4];
#pragma unroll
    for (int i = 0; i < 4; ++i)
#pragma unroll
        for (int j = 0; j < 4; ++j) acc[i][j] = (float4v)(0.f);

    int ar = tid >> 1;
    int ac = (tid & 1) * 16;
    int bn = tid & 127;
    int bq = (tid >> 7) * 16;
    const float* abase = x + (size_t)srow[ar] * D_DIM + ac;
    const float* bbase = w1 + (size_t)e * D_DIM * F_DIM + (size_t)bq * F_DIM + (n0 + bn);

    for (int k0 = 0; k0 < D_DIM; k0 += BK) {
        {
            const float* ap = abase + k0;
            float4v f0 = *(const float4v*)(ap);
            float4v f1 = *(const float4v*)(ap + 4);
            float4v f2 = *(const float4v*)(ap + 8);
            float4v f3 = *(const float4v*)(ap + 12);
            short8 s0, s1;
#pragma unroll
            for (int c = 0; c < 4; ++c) {
                s0[c] = f2b(f0[c]); s0[4 + c] = f2b(f1[c]);
                s1[c] = f2b(f2[c]); s1[4 + c] = f2b(f3[c]);
            }
            *(short8*)(&As[ar * LDK + ac]) = s0;
            *(short8*)(&As[ar * LDK + ac + 8]) = s1;
        }
        {
            const float* bp = bbase + (size_t)k0 * F_DIM;
            float v[16];
#pragma unroll
            for (int j = 0; j < 16; ++j) v[j] = bp[(size_t)j * F_DIM];
            short8 s0, s1;
#pragma unroll
            for (int j = 0; j < 8; ++j) { s0[j] = f2b(v[j]); s1[j] = f2b(v[8 + j]); }
            *(short8*)(&Bs[bn * LDK + bq]) = s0;
            *(short8*)(&Bs[bn * LDK + bq + 8]) = s1;
        }
        __syncthreads();
        short8 af[4], bfr[4];
#pragma unroll
        for (int i = 0; i < 4; ++i)
            af[i] = *(const short8*)(&As[(wm + i * 16 + (lane & 15)) * LDK + (lane >> 4) * 8]);
#pragma unroll
        for (int j = 0; j < 4; ++j)
            bfr[j] = *(const short8*)(&Bs[(wn + j * 16 + (lane & 15)) * LDK + (lane >> 4) * 8]);
#pragma unroll
        for (int i = 0; i < 4; ++i)
#pragma unroll
            for (int j = 0; j < 4; ++j)
                acc[i][j] = __builtin_amdgcn_mfma_f32_16x16x32_bf16(af[i], bfr[j], acc[i][j], 0, 0, 0);
        __syncthreads();
    }
    int rbase = (lane >> 4) * 4;
    int cbase = lane & 15;
#pragma unroll
    for (int i = 0; i < 4; ++i) {
#pragma unroll
        for (int r = 0; r < 4; ++r) {
            int row = wm + i * 16 + rbase + r;
            if (row < m_count) {
                short* hp = hbuf + (size_t)(row0 + row) * F_DIM + n0 + wn + cbase;
#pragma unroll
                for (int j = 0; j < 4; ++j) {
                    float s = acc[i][j][r];
                    float g = 0.5f * s * (1.f + erff(s * 0.70710678118f));
                    hp[j * 16] = f2b(g);
                }
            }
        }
    }
}

__global__ __launch_bounds__(256) void gemm2_kernel(const short* __restrict__ hbuf,
                                                    const float* __restrict__ w2,
                                                    const int* __restrict__ sorted,
                                                    const int* __restrict__ tmap,
                                                    float* __restrict__ out) {
    __shared__ short As[BM * LDK];
    __shared__ short Bs[BN * LDK];
    __shared__ int srow[BM];
    int mt = blockIdx.y;
    int m_count = tmap[mt * 3 + 2];
    if (m_count == 0) return;
    int e = tmap[mt * 3 + 0];
    int row0 = tmap[mt * 3 + 1];
    int n0 = blockIdx.x * BN;
    int tid = threadIdx.x;
    if (tid < BM) srow[tid] = sorted[row0 + (tid < m_count ? tid : m_count - 1)];
    __syncthreads();

    int lane = tid & 63, wave = tid >> 6;
    int wm = (wave & 1) * 64, wn = (wave >> 1) * 64;
    float4v acc[4][4];
#pragma unroll
    for (int i = 0; i < 4; ++i)
#pragma unroll
        for (int j = 0; j < 4; ++j) acc[i][j] = (float4v)(0.f);

    int ar = tid >> 1;
    int ac = (tid & 1) * 16;
    int bn = tid & 127;
    int bq = (tid >> 7) * 16;
    int arc = ar < m_count ? ar : m_count - 1;
    const short* abase = hbuf + (size_t)(row0 + arc) * F_DIM + ac;
    const float* bbase = w2 + (size_t)e * F_DIM * D_DIM + (size_t)bq * D_DIM + (n0 + bn);

    for (int k0 = 0; k0 < F_DIM; k0 += BK) {
        {
            const short* ap = abase + k0;
            *(short8*)(&As[ar * LDK + ac]) = *(const short8*)(ap);
            *(short8*)(&As[ar * LDK + ac + 8]) = *(const short8*)(ap + 8);
        }
        {
            const float* bp = bbase + (size_t)k0 * D_DIM;
            float v[16];
#pragma unroll
            for (int j = 0; j < 16; ++j) v[j] = bp[(size_t)j * D_DIM];
            short8 s0, s1;
#pragma unroll
            for (int j = 0; j < 8; ++j) { s0[j] = f2b(v[j]); s1[j] = f2b(v[8 + j]); }
            *(short8*)(&Bs[bn * LDK + bq]) = s0;
            *(short8*)(&Bs[bn * LDK + bq + 8]) = s1;
        }
        __syncthreads();
        short8 af[4], bfr[4];
#pragma unroll
        for (int i = 0; i < 4; ++i)
            af[i] = *(const short8*)(&As[(wm + i * 16 + (lane & 15)) * LDK + (lane >> 4) * 8]);
#pragma unroll
        for (int j = 0; j < 4; ++j)
            bfr[j] = *(const short8*)(&Bs[(wn + j * 16 + (lane & 15)) * LDK + (lane >> 4) * 8]);
#pragma unroll
        for (int i = 0; i < 4; ++i)
#pragma unroll
            for (int j = 0; j < 4; ++j)
                acc[i][j] = __builtin_amdgcn_mfma_f32_16x16x32_bf16(af[i], bfr[j], acc[i][j], 0, 0, 0);
        __syncthreads();
    }
    int rbase = (lane >> 4) * 4;
    int cbase = lane & 15;
#pragma unroll
    for (int i = 0; i < 4; ++i) {
#pragma unroll
        for (int r = 0; r < 4; ++r) {
            int row = wm + i * 16 + rbase + r;
            if (row < m_count) {
                float* op = out + (size_t)srow[row] * D_DIM + n0 + wn + cbase;
#pragma unroll
                for (int j = 0; j < 4; ++j) op[j * 16] = acc[i][j][r];
            }
        }
    }
}

extern "C" void kernel_launch(void* const* d_in, const int* in_sizes, int n_in,
                              void* d_out, int out_size, void* d_ws, size_t ws_size,
                              hipStream_t stream) {
    const float* x  = (const float*)d_in[0];
    const float* gw = (const float*)d_in[1];
    const float* w1 = (const float*)d_in[2];
    const float* w2 = (const float*)d_in[3];
    float* out = (float*)d_out;
    char* ws = (char*)d_ws;

    int* counts  = (int*)(ws);            // 8 ints
    int* offsets = (int*)(ws + 64);       // 9 ints
    int* tmap    = (int*)(ws + 128);      // 40*3 ints
    int* eid     = (int*)(ws + 1024);     // 4096 ints
    int* rnk     = (int*)(ws + 17408);    // 4096 ints
    int* sorted  = (int*)(ws + 33792);    // 4096 ints
    short* hbuf  = (short*)(ws + 51200);  // 4096*4096 bf16 = 33.55 MB

    const size_t HB  = 33554432ull;       // hbuf bytes
    const size_t XB  = 8388608ull;        // xb bytes  (4096*1024*2)
    const size_t WB  = 67108864ull;       // w1b/w2b bytes each (8*1024*4096*2)
    short* xb  = (short*)(ws + 51200 + HB);
    short* w1b = (short*)(ws + 51200 + HB + XB);
    short* w2b = (short*)(ws + 51200 + HB + XB + WB);
    const size_t need = 51200ull + HB + XB + 2ull * WB;   // ~176.2 MB
    bool fast = ws_size >= need;

    hipMemsetAsync(counts, 0, 32, stream);
    router_kernel<<<T_TOK / 4, 256, 0, stream>>>(x, gw, fast ? xb : (short*)0, eid, rnk, counts);

    if (fast) {
        hipMemsetAsync(out, 0, (size_t)T_TOK * D_DIM * 4, stream);
        // w1: [e][d=1024][f=4096] -> w1b [e][f][d]
        tconv_kernel<<<dim3(F_DIM / 64, D_DIM / 64, E_EXP), 256, 0, stream>>>(w1, w1b, D_DIM, F_DIM);
        // w2: [e][f=4096][d=1024] -> w2b [e][d][f]
        tconv_kernel<<<dim3(D_DIM / 64, F_DIM / 64, E_EXP), 256, 0, stream>>>(w2, w2b, F_DIM, D_DIM);
    }

    prefix_kernel<<<1, 64, 0, stream>>>(counts, offsets, tmap);
    scatter_kernel<<<T_TOK / 256, 256, 0, stream>>>(eid, rnk, offsets, sorted);

    if (fast) {
        gemm1_bf16<<<dim3(F_DIM / BN, MAX_TILES), 256, 0, stream>>>(xb, w1b, sorted, tmap, hbuf);
        gemm2_bf16<<<dim3(D_DIM / BN, MAX_TILES, KSPLIT), 256, 0, stream>>>(hbuf, w2b, sorted, tmap, out);
    } else {
        gemm1_kernel<<<dim3(F_DIM / BN, MAX_TILES), 256, 0, stream>>>(x, w1, sorted, tmap, hbuf);
        gemm2_kernel<<<dim3(D_DIM / BN, MAX_TILES), 256, 0, stream>>>(hbuf, w2, sorted, tmap, out);
    }
}